// Round 8
// baseline (174.507 us; speedup 1.0000x reference)
//
#include <hip/hip_runtime.h>
#include <hip/hip_bf16.h>
#include <math.h>

// ArcFace loss, MI355X. B=2048, D=512, C=32768.
// R15b: R15 with compile fix (update_dpp ctrl must be an immediate ->
// template<int CTRL>). R14 was DS-pipe-bound (MfmaUtil 17% = 13.4us MFMA
// busy vs 77us duration; main-loop ds_reads ~35us + 80 shfl_xor/thread
// epilogue (ds_swizzle = DS pipe) ~25us). R15 moves work off the DS pipe:
// (1) A fragments load DIRECTLY from global (L2) into registers,
//     prefetched one BK-128 iteration ahead (fb8 rows are pre-permuted,
//     so a fragment = two contiguous 16B loads; lanes l/l+32 cover full
//     64B sectors). Removes A ds_reads (-33% main-loop DS) and A staging.
//     +32 VGPRs ping-pong: ~80 live <= 96 arch half of (512,4) cap.
// (2) Epilogue row-sums via DPP (v_add_f32 row_shr:1/2/4/8 + row_bcast:15,
//     bound_ctrl=0): pure VALU, replaces 80 ds_swizzle + shfl tree;
//     lanes 31/63 hold the 32-col sums.
// MX-scaled fp8 MFMA (32x32x64, unit scales 0x7F) and all layouts
// bit-exact since R11. B staging/XOR-rotation/ping-pong/prep/loss
// unchanged from R14.

#define BN 2048
#define DK 512
#define CN 32768

typedef __attribute__((ext_vector_type(4))) float floatx4;
typedef __attribute__((ext_vector_type(16))) float floatx16;
typedef __attribute__((ext_vector_type(2))) long longx2;
typedef __attribute__((ext_vector_type(4))) long longx4;
typedef __attribute__((ext_vector_type(8))) int intx8;

__device__ inline float dot4(floatx4 a, floatx4 b) {
  return a.x * b.x + a.y * b.y + a.z * b.z + a.w * b.w;
}

__device__ inline int pack_fp8x4(floatx4 v) {
  int r = __builtin_amdgcn_cvt_pk_fp8_f32(v.x, v.y, 0, false);
  r = __builtin_amdgcn_cvt_pk_fp8_f32(v.z, v.w, r, true);
  return r;
}

// dword j (0..15) of a 64B slab -> MFMA-ready position:
// q=(j>>1)&3 (8B piece), p=j>>3 (k-step), dest = q*4 + p*2 + (j&1)
__device__ inline int permute16(int j) {
  return ((j >> 1) & 3) * 4 + (j >> 3) * 2 + (j & 1);
}

__device__ inline void async_ld16(const void* g, void* l) {
  __builtin_amdgcn_global_load_lds(
      (const __attribute__((address_space(1))) void*)g,
      (__attribute__((address_space(3))) void*)l, 16, 0, 0);
}

// DPP-based add: v += dpp(v, CTRL); invalid lanes contribute 0 (bound_ctrl).
// 0x111..0x11F = row_shr:1..15, 0x142 = row_bcast15.
template <int CTRL>
__device__ inline float dpp_add(float v) {
  int t = __builtin_amdgcn_update_dpp(0, __float_as_int(v), CTRL, 0xf, 0xf,
                                      true);
  return v + __int_as_float(t);
}

// ---- kernel 1: fused prep -> fp8 rows (512 B each), MFMA-ready byte order.
__global__ void prep_kernel(const float* __restrict__ feat,
                            const int* __restrict__ y,
                            const float* __restrict__ w,
                            int* __restrict__ fb8,     // [BN][128] dwords
                            int* __restrict__ wb8,     // [CN][128] dwords
                            float* __restrict__ tgt,
                            float* __restrict__ rowsum) {
  const int wave = threadIdx.x >> 6;
  const int l = threadIdx.x & 63;
  const int d0 = ((l >> 4) * 16)       + permute16(l & 15);
  const int d1 = ((4 + (l >> 4)) * 16) + permute16(l & 15);
  if (blockIdx.x < 8192) {
    const int row = blockIdx.x * 4 + wave;
    const floatx4* src = (const floatx4*)(w + (size_t)row * DK);
    floatx4 v0 = src[l];
    floatx4 v1 = src[64 + l];
    float s = dot4(v0, v0) + dot4(v1, v1);
#pragma unroll
    for (int off = 1; off < 64; off <<= 1) s += __shfl_xor(s, off, 64);
    const float scale = 1.0f / fmaxf(sqrtf(s), 1e-12f);
    v0 *= scale; v1 *= scale;
    int* db = wb8 + (size_t)row * 128;
    db[d0] = pack_fp8x4(v0);
    db[d1] = pack_fp8x4(v1);
  } else {
    const int i = (blockIdx.x - 8192) * 4 + wave;
    const floatx4* src = (const floatx4*)(feat + (size_t)i * DK);
    floatx4 v0 = src[l];
    floatx4 v1 = src[64 + l];
    const int cls = y[i];
    const floatx4* wr = (const floatx4*)(w + (size_t)cls * DK);
    floatx4 w0 = wr[l], w1 = wr[64 + l];
    float s  = dot4(v0, v0) + dot4(v1, v1);
    float d  = dot4(v0, w0) + dot4(v1, w1);
    float wn = dot4(w0, w0) + dot4(w1, w1);
#pragma unroll
    for (int off = 1; off < 64; off <<= 1) {
      s  += __shfl_xor(s, off, 64);
      d  += __shfl_xor(d, off, 64);
      wn += __shfl_xor(wn, off, 64);
    }
    const float fscale = 1.0f / fmaxf(sqrtf(s), 1e-12f);
    v0 *= fscale; v1 *= fscale;
    int* db = fb8 + (size_t)i * 128;
    db[d0] = pack_fp8x4(v0);
    db[d1] = pack_fp8x4(v1);
    if (l == 0) {
      tgt[i] = d * fscale / fmaxf(sqrtf(wn), 1e-12f);
      rowsum[i] = 0.0f;
    }
  }
}

// ---- kernel 2: 128(M)x128(N) MX-fp8 MFMA GEMM (32x32x64, unit scales),
// 512 threads (8 waves, 4Mx2N, 32x64 per wave), BK=128 per barrier,
// B via ping-pong LDS, A direct-from-global (prefetched), DPP epilogue.
__launch_bounds__(512, 4)
__global__ void gemm_exp_kernel(const char* __restrict__ fb8,   // [BN][512] B
                                const char* __restrict__ wb8,   // [CN][512] B
                                float* __restrict__ rowsum) {
  __shared__ char Bs[2][2 * 128 * 64];   // 2 bufs x 2 slabs x 8 KB = 32 KB
  __shared__ float lsum[128];

  const int tid  = threadIdx.x;
  const int wave = tid >> 6;
  const int lane = tid & 63;

  // XCD swizzle: n bits {b11..b7}=Ngroup, {b6..b3}=M-tile, {b2..b0}=xcd.
  // N-tile = Ngroup*8 + xcd, so XCD x owns N-tiles == x (mod 8): bijective.
  const int n = blockIdx.x;
  const int tileM = ((n >> 3) & 15) * 128;
  const int tileN = (((n >> 7) << 3) | (n & 7)) * 128;

  const int wm = (wave & 3) * 32;   // wave M offset (0..96)
  const int wn = (wave >> 2) * 64;  // wave N offset (0 or 64)

  if (tid < 128) lsum[tid] = 0.0f;  // covered by first K-loop barrier

  floatx16 acc[2];
#pragma unroll
  for (int tj = 0; tj < 2; ++tj)
#pragma unroll
    for (int r = 0; r < 16; ++r)
      acc[tj][r] = 0.0f;

  // B staging: chunk c -> row c>>2, stored pos c&3, fetched global unit
  // (c&3)^((row>>1)&3). Thread t stages chunk t of slab lo (LDS t*16) and
  // chunk t of slab hi (8192 + t*16). LDS dest = wave-uniform base
  // (wave*1024); HW adds lane*16.
  const int rowL = tid >> 2;                         // rows 0..127
  const int uL   = (tid & 3) ^ ((rowL >> 1) & 3);
  const char* gB = wb8 + (size_t)(tileN + rowL) * DK + uL * 16;
  const int ldsO = wave * 1024;

  // A direct-from-global: lane reads its fragment (row = tileM+wm+(lane&31),
  // 32 B at byte q2*16 of each 64B slab; fb8 rows are permute16'd already,
  // unrotated). Per BK-128 iteration: 4x 16B loads at {0,16,64,80}.
  const int r31 = lane & 31;
  const int q2  = (lane >> 5) * 2;
  const longx2* gA = (const longx2*)(fb8 + (size_t)(tileM + wm + r31) * DK
                                     + q2 * 16);

  // hoisted B fragment LDS byte-offsets (slab-local, loop-invariant).
  // Lane: row = wn + tj*32 + (lane&31), stored pos of unit u is
  // u ^ ((row>>1)&3).
  int offB0[2], offB1[2];
#pragma unroll
  for (int tj = 0; tj < 2; ++tj) {
    const int row = wn + tj * 32 + r31;
    const int rot = (row >> 1) & 3;
    offB0[tj] = row * 64 + ((q2    ) ^ rot) * 16;
    offB1[tj] = row * 64 + ((q2 + 1) ^ rot) * 16;
  }

  // A prefetch registers: [parity][slab][16B-half]; statically indexed
  // (loop fully unrolled) to stay in registers.
  longx2 apre[2][2][2];

  // prologue: stage iteration 0 (B slabs 0,1) into buffer 0; A loads for it 0.
  async_ld16(gB,      &Bs[0][ldsO]);
  async_ld16(gB + 64, &Bs[0][8192 + ldsO]);
  gB += 128;
  apre[0][0][0] = gA[0];  apre[0][0][1] = gA[1];   // slab 0: bytes {0,16}
  apre[0][1][0] = gA[4];  apre[0][1][1] = gA[5];   // slab 1: bytes {64,80}
  gA += 8;

#pragma unroll
  for (int it = 0; it < DK / 128; ++it) {
    const int cur = it & 1;
    // Barrier: (a) drains this wave's vmcnt -> Bs[cur] resident and
    // apre[cur] loaded (all issued one full BK-128 iteration ago);
    // (b) all waves done with Bs[cur^1].
    __syncthreads();
    if (it < DK / 128 - 1) {
      const int nxt = cur ^ 1;
      async_ld16(gB,      &Bs[nxt][ldsO]);
      async_ld16(gB + 64, &Bs[nxt][8192 + ldsO]);
      gB += 128;
      apre[nxt][0][0] = gA[0];  apre[nxt][0][1] = gA[1];
      apre[nxt][1][0] = gA[4];  apre[nxt][1][1] = gA[5];
      gA += 8;
    }

#pragma unroll
    for (int ks = 0; ks < 2; ++ks) {
      const char* Bb = &Bs[cur][ks * 8192];
      intx8 a, b[2];
      a = (intx8)(longx4){apre[cur][ks][0].x, apre[cur][ks][0].y,
                          apre[cur][ks][1].x, apre[cur][ks][1].y};
#pragma unroll
      for (int tj = 0; tj < 2; ++tj) {
        longx2 lo = *(const longx2*)(Bb + offB0[tj]);
        longx2 hi = *(const longx2*)(Bb + offB1[tj]);
        b[tj] = (intx8)(longx4){lo.x, lo.y, hi.x, hi.y};
      }
      // 2 MX-scaled MFMAs, K=64, unit scales (0x7F = 2^0): per-product
      // identical to the non-scaled fp8 path; A and B share the same
      // k-permutation so the contraction is exact (bit-exact since R11).
#pragma unroll
      for (int tj = 0; tj < 2; ++tj)
        acc[tj] = __builtin_amdgcn_mfma_scale_f32_32x32x64_f8f6f4(
            a, b[tj], acc[tj],
            0, 0, 0, 0x7f7f7f7f, 0, 0x7f7f7f7f);
    }
  }

  // epilogue: rowsum[m] += sum_n exp(64 * wf[m][n]) — pure-VALU DPP
  // reduction (no DS pipe). C/D 32x32 layout: col = lane&31,
  // row = (reg&3) + 8*(reg>>2) + 4*(lane>>5). row_shr chain sums lanes
  // within each 16-row toward lane 15/31/47/63; row_bcast15 folds the low
  // 16 into the high 16 of each 32-half: lane31 = sum(cols 0..31) for its
  // half's row, lane63 likewise for the q=1 row.
  const int qrow = (lane >> 5) * 4;
#pragma unroll
  for (int r = 0; r < 16; ++r) {
    float v = __expf(64.0f * acc[0][r]) + __expf(64.0f * acc[1][r]);
    v = dpp_add<0x111>(v);   // row_shr:1
    v = dpp_add<0x112>(v);   // row_shr:2
    v = dpp_add<0x114>(v);   // row_shr:4
    v = dpp_add<0x118>(v);   // row_shr:8
    v = dpp_add<0x142>(v);   // row_bcast15
    if ((lane & 31) == 31)
      atomicAdd(&lsum[wm + qrow + (r & 3) + 8 * (r >> 2)], v);
  }
  __syncthreads();
  if (tid < 128)
    atomicAdd(&rowsum[tileM + tid], lsum[tid]);
}

// ---- kernel 3: final loss
__global__ void loss_kernel(const float* __restrict__ tgt,
                            const float* __restrict__ rowsum,
                            float* __restrict__ out) {
  __shared__ float wsum[8];
  const int t = threadIdx.x;
  float sum = 0.f;
  const float cM = 0.87758256189037271f;  // cos(0.5)
  const float sM = 0.47942553860420301f;  // sin(0.5)
  for (int i = t; i < BN; i += 512) {
    const float tg_raw = tgt[i];
    const float tg = fminf(fmaxf(tg_raw, -1.f + 1e-7f), 1.f - 1e-7f);
    const float num = 64.f * (tg * cM - sqrtf(fmaxf(1.f - tg * tg, 0.f)) * sM);
    const float den = expf(num) + rowsum[i] - expf(64.f * tg_raw);
    sum += num - logf(den);
  }
#pragma unroll
  for (int off = 1; off < 64; off <<= 1) sum += __shfl_xor(sum, off, 64);
  if ((t & 63) == 0) wsum[t >> 6] = sum;
  __syncthreads();
  if (t == 0) {
    float tot = 0.f;
#pragma unroll
    for (int k = 0; k < 8; ++k) tot += wsum[k];
    out[0] = -tot * (1.0f / (float)BN);
  }
}

extern "C" void kernel_launch(void* const* d_in, const int* in_sizes, int n_in,
                              void* d_out, int out_size, void* d_ws, size_t ws_size,
                              hipStream_t stream) {
  const float* features = (const float*)d_in[0];
  const int*   y_true   = (const int*)d_in[1];
  const float* weight   = (const float*)d_in[2];
  float* out = (float*)d_out;

  char* ws = (char*)d_ws;
  char* wb8    = ws;                          // 16 MB
  char* fb8    = ws + 16777216;               //  1 MB
  float* tgt    = (float*)(ws + 17825792);    //  8 KB
  float* rowsum = (float*)(ws + 17833984);    //  8 KB

  prep_kernel<<<8192 + 512, 256, 0, stream>>>(features, y_true, weight,
                                              (int*)fb8, (int*)wb8, tgt, rowsum);
  gemm_exp_kernel<<<4096, 512, 0, stream>>>(fb8, wb8, rowsum);
  loss_kernel<<<1, 512, 0, stream>>>(tgt, rowsum, out);
}